// Round 17
// baseline (63.115 us; speedup 1.0000x reference)
//
#include <hip/hip_runtime.h>
#include <math.h>

// Problem dims: UNITS=512, MEM=16384, BATCH=64
// d_out offsets (floats): h, c, read, m, c_wu, c_wlu, c_wr
#define OUT_H    0
#define OUT_C    32768
#define OUT_READ 65536
#define OUT_M    98304
#define OUT_CWU  8486912
#define OUT_CWLU 9535488
#define OUT_CWR  10584064

// preact scratch (4*294912 floats) lives in OUT_M region, consumed by k_gates
// before k_update overwrites m. Everything else in d_ws (ws_size ~268MB).
// ws offsets (floats) — ushort buffers: floats = ushort_count/2 (CHECKED):
//   nkf  32768 ush = 16384 fl: [0,16384)
//   hbf  32768 ush = 16384 fl: [16384,32768)
//   cwwf 256*4096 ush = 524288 fl: [65664,589952)
//   cwrf 256*4096 ush = 524288 fl: [589952,1114240)
//   rpart 32*32768 = 1M fl: [1114240,2162816)
#define WS_NKF   0
#define WS_HBF   16384
#define WS_PMIN  32768      // 256*64 partial min values
#define WS_PIDX  49152      // 256*64 partial min indices (int)
#define WS_MINF  65536      // 64 final min
#define WS_IDXF  65600      // 64 final argmin (int)
#define WS_CWWF  65664
#define WS_CWRF  589952
#define WS_RPART 1114240

typedef short bf16x8 __attribute__((ext_vector_type(8)));
typedef float f32x4  __attribute__((ext_vector_type(4)));

__device__ __forceinline__ float hsig(float x) {
    return fminf(fmaxf(0.2f * x + 0.5f, 0.f), 1.f);
}
__device__ __forceinline__ unsigned short f2bf(float x) {
    unsigned u = __float_as_uint(x);
    return (unsigned short)((u + 0x7fffu + ((u >> 16) & 1u)) >> 16);
}

// ---------------------------------------------------------------------------
// K1: preactivations via MFMA bf16. (verified round 15)
// grid 288 = 72 col-tiles(64) x 4 K-quarters(128). Block 256.
// ---------------------------------------------------------------------------
__global__ __launch_bounds__(256) void k_preact(
    const float* __restrict__ inputs, const float* __restrict__ h_tm1,
    const float* __restrict__ r_tm1, const float* __restrict__ wk,
    const float* __restrict__ rk, float* __restrict__ pre)
{
    __shared__ alignas(16) unsigned short Afr[8192];   // 16 KB
    __shared__ alignas(16) unsigned short Bfr[8192];   // 16 KB
    const int cb = blockIdx.x % 72, kh = blockIdx.x / 72;
    const int vcol0 = cb * 64;
    const float* A; const float* W; int wstride, wcol0;
    if (vcol0 < 2048)      { A = inputs; W = wk; wstride = 2048; wcol0 = vcol0; }
    else if (vcol0 < 4096) { A = h_tm1;  W = rk; wstride = 2560; wcol0 = vcol0 - 2048; }
    else                   { A = r_tm1;  W = rk; wstride = 2560; wcol0 = 2048 + (vcol0 - 4096); }
    const int tid = threadIdx.x;
    const int w = tid >> 6, lane = tid & 63;
    const int lhi = lane >> 4, llo = lane & 15;

    {
        const int koct = tid & 15;
        const int s = koct >> 2;
        #pragma unroll
        for (int i = 0; i < 4; ++i) {
            int row = i * 16 + (tid >> 4);
            const float* src = &A[row * 512 + kh * 128 + koct * 8];
            float4 x0 = *(const float4*)src;
            float4 x1 = *(const float4*)&src[4];
            int ln = (row & 15) + 16 * (koct & 3);
            int rt = row >> 4;
            union { unsigned short hx[8]; uint4 v; } pk;
            pk.hx[0] = f2bf(x0.x); pk.hx[1] = f2bf(x0.y);
            pk.hx[2] = f2bf(x0.z); pk.hx[3] = f2bf(x0.w);
            pk.hx[4] = f2bf(x1.x); pk.hx[5] = f2bf(x1.y);
            pk.hx[6] = f2bf(x1.z); pk.hx[7] = f2bf(x1.w);
            *(uint4*)&Afr[((s * 4 + rt) * 64 + ln) << 3] = pk.v;
        }
    }
    #pragma unroll
    for (int q = 0; q < 8; ++q) {
        int idx = q * 256 + tid;
        int krow = idx >> 4;
        int c4 = (idx & 15) * 4;
        float4 wv = *(const float4*)&W[(size_t)(kh * 128 + krow) * wstride + wcol0 + c4];
        int s = krow >> 5, lh = (krow & 31) >> 3, e = krow & 7;
        float ws4[4] = { wv.x, wv.y, wv.z, wv.w };
        #pragma unroll
        for (int j = 0; j < 4; ++j) {
            int col = c4 + j;
            int tc = col >> 4;
            int ln = (col & 15) + 16 * lh;
            Bfr[(((s * 4 + tc) * 64 + ln) << 3) + e] = f2bf(ws4[j]);
        }
    }
    __syncthreads();

    f32x4 acc[4] = {};
    #pragma unroll
    for (int s = 0; s < 4; ++s) {
        bf16x8 af = *(const bf16x8*)&Afr[((s * 4 + w) * 64 + lane) << 3];
        #pragma unroll
        for (int tc = 0; tc < 4; ++tc) {
            bf16x8 bf = *(const bf16x8*)&Bfr[((s * 4 + tc) * 64 + lane) << 3];
            acc[tc] = __builtin_amdgcn_mfma_f32_16x16x32_bf16(af, bf, acc[tc], 0, 0, 0);
        }
    }

    float* dst = pre + (size_t)kh * 294912;
    #pragma unroll
    for (int tc = 0; tc < 4; ++tc) {
        #pragma unroll
        for (int reg = 0; reg < 4; ++reg) {
            int row = w * 16 + lhi * 4 + reg;
            dst[row * 4608 + vcol0 + tc * 16 + llo] = acc[tc][reg];
        }
    }
}

// ---------------------------------------------------------------------------
// K1c: gate fusion (sums 4 K-quarters) -> h, c; fused L2-norm + bf16 packing.
// grid 64 (one block per batch column b), 256 threads, 2 u per thread.
// ---------------------------------------------------------------------------
__global__ __launch_bounds__(256) void k_gates(
    const float* __restrict__ pre, const float* __restrict__ bias,
    const float* __restrict__ c_tm1, float* __restrict__ out,
    unsigned short* __restrict__ nkf, unsigned short* __restrict__ hbf)
{
    int b = blockIdx.x, t = threadIdx.x;
    const float* p0 = pre + b * 4608;
    const float* p1 = pre + 294912 + b * 4608;
    const float* p2 = pre + 2 * 294912 + b * 4608;
    const float* p3 = pre + 3 * 294912 + b * 4608;
    float hh[2], cc[2];
    #pragma unroll
    for (int q = 0; q < 2; ++q) {
        int u = t + q * 256;
        #define S4(o) (p0[o] + p1[o] + p2[o] + p3[o])
        float xi = S4(u)        + bias[u];
        float xf = S4(512 + u)  + bias[512 + u];
        float xc = S4(1024 + u) + bias[1024 + u];
        float xo = S4(1536 + u) + bias[1536 + u];
        float hi = S4(2048 + u);
        float hf = S4(2560 + u);
        float hc = S4(3072 + u);
        float ho = S4(3584 + u);
        float ri = S4(4096 + u);
        #undef S4
        float ig = hsig(xi + hi + ri);
        float fg = hsig(xf + hf);
        cc[q] = fg * c_tm1[b * 512 + u] + ig * tanhf(xc + hc);
        float og = hsig(xo + ho);
        hh[q] = og * tanhf(cc[q]);
        out[OUT_H + b * 512 + u] = hh[q];
        out[OUT_C + b * 512 + u] = cc[q];
    }
    float ss = hh[0] * hh[0] + hh[1] * hh[1];
    __shared__ float red[4];
    for (int m = 1; m < 64; m <<= 1) ss += __shfl_xor(ss, m);
    if ((t & 63) == 0) red[t >> 6] = ss;
    __syncthreads();
    float tot = red[0] + red[1] + red[2] + red[3];
    float rn = rsqrtf(fmaxf(tot, 1e-12f));
    #pragma unroll
    for (int q = 0; q < 2; ++q) {
        int u = t + q * 256;
        int s = u >> 5, n = b >> 4;
        int lane = (b & 15) + 16 * ((u & 31) >> 3);
        int e = u & 7;
        nkf[(((s * 4 + n) * 64 + lane) << 3) + e] = f2bf(hh[q] * rn);
        int s2 = b >> 5, N = u >> 4;
        int l2 = (u & 15) + 16 * ((b & 31) >> 3);
        int e2 = b & 7;
        hbf[(((s2 * 32 + N) * 64 + l2) << 3) + e2] = f2bf(hh[q]);
    }
}

// ---------------------------------------------------------------------------
// K2: cos GEMM via MFMA bf16, 512 threads (8 waves). 64 rows/block, grid 256.
// Wave w: row-tile (w&3), K-half (w>>2); halves reduced via LDS OVERLAY in
// Af[8192..16384) ushorts (16 KB) — total LDS ~65.5 KB -> 2 blocks/CU.
// Fused: row-norm, softmax, c_wr/c_wu, min partials, cww+cwr A-frags.
// ---------------------------------------------------------------------------
__global__ __launch_bounds__(512) void k_cos(
    const float* __restrict__ m_tm1, const unsigned short* __restrict__ nkf,
    const float* __restrict__ cwr_tm1, const float* __restrict__ cwlu_tm1,
    const float* __restrict__ cwu_tm1, const float* __restrict__ wgp,
    float* out, float* __restrict__ pmin, int* __restrict__ pidx,
    unsigned short* __restrict__ cwwf, unsigned short* __restrict__ cwrf)
{
    __shared__ alignas(16) unsigned short Af[4096 * 8];   // 64 KB: all 16 k-steps
    __shared__ float rn[64];
    __shared__ float pmv[4][64];
    __shared__ int   pmi[4][64];
    const int row0 = blockIdx.x * 64;
    const int tid = threadIdx.x;
    const int w = tid >> 6, lane = tid & 63;
    f32x4 acc[4] = {};
    float ssp[8] = {};

    // --- stage all 64 rows x 512 k as bf16 A-frags; wave w stages row i*8+w ---
    #pragma unroll
    for (int i = 0; i < 8; ++i) {
        int r = i * 8 + w;
        int koct = lane;                           // 0..63 k-octets
        const float* src = &m_tm1[(size_t)(row0 + r) * 512 + koct * 8];
        float4 x0 = *(const float4*)src;
        float4 x1 = *(const float4*)&src[4];
        ssp[i] += x0.x*x0.x + x0.y*x0.y + x0.z*x0.z + x0.w*x0.w
                + x1.x*x1.x + x1.y*x1.y + x1.z*x1.z + x1.w*x1.w;
        int s_l = koct >> 2, rt = r >> 4;
        int ln = ((r & 15) + ((koct & 3) << 4)) ^ (s_l & 7);
        union { unsigned short hx[8]; uint4 v; } pk;
        pk.hx[0] = f2bf(x0.x); pk.hx[1] = f2bf(x0.y);
        pk.hx[2] = f2bf(x0.z); pk.hx[3] = f2bf(x0.w);
        pk.hx[4] = f2bf(x1.x); pk.hx[5] = f2bf(x1.y);
        pk.hx[6] = f2bf(x1.z); pk.hx[7] = f2bf(x1.w);
        *(uint4*)&Af[((s_l * 4 + rt) * 64 + ln) << 3] = pk.v;
    }
    #pragma unroll
    for (int i = 0; i < 8; ++i) {
        float v = ssp[i];
        v += __shfl_xor(v, 1); v += __shfl_xor(v, 2);
        v += __shfl_xor(v, 4); v += __shfl_xor(v, 8);
        v += __shfl_xor(v, 16); v += __shfl_xor(v, 32);
        if (lane == 0) rn[i * 8 + w] = v;
    }
    __syncthreads();

    // --- MFMA: wave w = row-tile (w&3), K-half (w>>2): 8 k-steps ---
    {
        const int wt = w & 3, kh2 = w >> 2;
        for (int s_l = 0; s_l < 8; ++s_l) {
            int s = kh2 * 8 + s_l;
            int lnx = lane ^ (s & 7);
            bf16x8 af = *(const bf16x8*)&Af[((s * 4 + wt) * 64 + lnx) << 3];
            #pragma unroll
            for (int n = 0; n < 4; ++n) {
                bf16x8 bf = *(const bf16x8*)&nkf[((s * 4 + n) * 64 + lane) << 3];
                acc[n] = __builtin_amdgcn_mfma_f32_16x16x32_bf16(af, bf, acc[n], 0, 0, 0);
            }
        }
    }
    // --- reduce K-halves via overlay at Af[8192..16384) ushorts (16 KB) ---
    __syncthreads();                         // all MFMA reads of Af done
    float* redf = (float*)&Af[8192];
    if (w >= 4) {
        #pragma unroll
        for (int n = 0; n < 4; ++n)
            *(f32x4*)&redf[((((w - 4) * 4 + n) * 64) + lane) * 4] = acc[n];
    }
    __syncthreads();
    if (w < 4) {
        #pragma unroll
        for (int n = 0; n < 4; ++n) {
            f32x4 o = *(const f32x4*)&redf[(((w * 4 + n) * 64) + lane) * 4];
            acc[n][0] += o[0]; acc[n][1] += o[1]; acc[n][2] += o[2]; acc[n][3] += o[3];
        }
    }

    const float wg = 1.f / (1.f + expf(-wgp[0]));
    const int lhi = lane >> 4, llo = lane & 15;
    if (w < 4) {
        float rsq[4];
        #pragma unroll
        for (int reg = 0; reg < 4; ++reg) {
            int rl = w * 16 + lhi * 4 + reg;
            rsq[reg] = rsqrtf(fmaxf(rn[rl], 1e-12f));
        }
        float bmv[4] = { INFINITY, INFINITY, INFINITY, INFINITY };
        int   bmi[4] = { 0x7fffffff, 0x7fffffff, 0x7fffffff, 0x7fffffff };
        #pragma unroll
        for (int reg = 0; reg < 4; ++reg) {
            int rl = w * 16 + lhi * 4 + reg;   // r_local in [0,64)
            int r = row0 + rl;
            float c0 = acc[0][reg] * rsq[reg];
            float c1 = acc[1][reg] * rsq[reg];
            float c2 = acc[2][reg] * rsq[reg];
            float c3 = acc[3][reg] * rsq[reg];
            float mx = fmaxf(fmaxf(c0, c1), fmaxf(c2, c3));
            mx = fmaxf(mx, __shfl_xor(mx, 1));
            mx = fmaxf(mx, __shfl_xor(mx, 2));
            mx = fmaxf(mx, __shfl_xor(mx, 4));
            mx = fmaxf(mx, __shfl_xor(mx, 8));
            float e0 = expf(c0 - mx), e1 = expf(c1 - mx);
            float e2 = expf(c2 - mx), e3 = expf(c3 - mx);
            float sm = e0 + e1 + e2 + e3;
            sm += __shfl_xor(sm, 1);
            sm += __shfl_xor(sm, 2);
            sm += __shfl_xor(sm, 4);
            sm += __shfl_xor(sm, 8);
            float inv = 1.f / sm;
            float pv[4] = { e0 * inv, e1 * inv, e2 * inv, e3 * inv };
            #pragma unroll
            for (int n = 0; n < 4; ++n) {
                int g = r * 64 + n * 16 + llo;
                float p = pv[n];
                out[OUT_CWR + g] = p;
                float wr = cwr_tm1[g], wl = cwlu_tm1[g], wu = cwu_tm1[g];
                float cww = wg * wr + (1.f - wg) + wl;
                float cwu = 0.95f * wu + p + cww;
                out[OUT_CWU + g] = cwu;
                // c_ww A-frag for k_update: A[row=rl][k=b=n*16+llo]
                {
                    int rowl16 = lhi * 4 + reg;
                    int s2 = n >> 1;
                    int l2 = rowl16 + 16 * (((n & 1) << 1) + (llo >> 3));
                    Af[(((s2 * 4 + w) * 64 + l2) << 3) + (llo & 7)] = f2bf(cww);
                }
                // c_wr A-frag for k_read_part: A[row=b=n*16+llo][k=rl]
                {
                    int sA = rl >> 5;
                    int lf = llo + 16 * ((rl & 31) >> 3);
                    Af[4096 + (((sA * 4 + n) * 64 + lf) << 3) + (rl & 7)] = f2bf(p);
                }
                if (cwu < bmv[n]) { bmv[n] = cwu; bmi[n] = r; }
            }
        }
        #pragma unroll
        for (int n = 0; n < 4; ++n) {
            #pragma unroll
            for (int mk = 16; mk <= 32; mk <<= 1) {
                float ov = __shfl_xor(bmv[n], mk);
                int   oi = __shfl_xor(bmi[n], mk);
                if (ov < bmv[n] || (ov == bmv[n] && oi < bmi[n])) { bmv[n] = ov; bmi[n] = oi; }
            }
        }
        if (lhi == 0) {
            #pragma unroll
            for (int n = 0; n < 4; ++n) { pmv[w][n * 16 + llo] = bmv[n]; pmi[w][n * 16 + llo] = bmi[n]; }
        }
    }
    __syncthreads();
    // copy both 4096-ushort frag blocks out (512 uint4 each; all 512 threads)
    {
        uint4* dstW = (uint4*)&cwwf[(size_t)blockIdx.x * 4096];
        uint4* dstR = (uint4*)&cwrf[(size_t)blockIdx.x * 4096];
        const uint4* srcp = (const uint4*)Af;
        dstW[tid] = srcp[tid];
        dstR[tid] = srcp[512 + tid];
    }
    if (tid < 64) {
        float bv = pmv[0][tid]; int bi = pmi[0][tid];
        #pragma unroll
        for (int q = 1; q < 4; ++q) {
            float v = pmv[q][tid]; int i2 = pmi[q][tid];
            if (v < bv || (v == bv && i2 < bi)) { bv = v; bi = i2; }
        }
        pmin[blockIdx.x * 64 + tid] = bv;
        pidx[blockIdx.x * 64 + tid] = bi;
    }
}

// ---------------------------------------------------------------------------
// K5: read partials via MFMA bf16 + embedded minfinal.
// grid 256 = 32 row-splits(512 rows) x 8 u-splits(64). rpart: 32 partials.
// ---------------------------------------------------------------------------
__global__ __launch_bounds__(256) void k_read_part(
    const float* __restrict__ m_tm1, const unsigned short* __restrict__ cwrf,
    float* __restrict__ part,
    const float* __restrict__ pmin, const int* __restrict__ pidx,
    float* __restrict__ minf, int* __restrict__ idxf)
{
    __shared__ alignas(16) unsigned short Mf[8192];   // 16 KB: m B-frags
    __shared__ float sv[4]; __shared__ int si[4];
    const int bid = blockIdx.x;
    const int tid = threadIdx.x;
    if (bid < 64) {   // embedded minfinal (block-uniform branch)
        int col = bid;
        float bv = pmin[tid * 64 + col];
        int   bi = pidx[tid * 64 + col];
        for (int mk = 1; mk < 64; mk <<= 1) {
            float ov = __shfl_xor(bv, mk);
            int   oi = __shfl_xor(bi, mk);
            if (ov < bv || (ov == bv && oi < bi)) { bv = ov; bi = oi; }
        }
        if ((tid & 63) == 0) { sv[tid >> 6] = bv; si[tid >> 6] = bi; }
        __syncthreads();
        if (tid == 0) {
            #pragma unroll
            for (int q = 1; q < 4; ++q) {
                if (sv[q] < bv || (sv[q] == bv && si[q] < bi)) { bv = sv[q]; bi = si[q]; }
            }
            minf[col] = bv; idxf[col] = bi;
        }
    }
    const int rs = bid >> 3, us = bid & 7;
    const int row0 = rs * 512, u0 = us * 64;
    const int w = tid >> 6, lane = tid & 63;
    f32x4 acc[4] = {};
    for (int ch = 0; ch < 4; ++ch) {
        const int r0 = row0 + ch * 128;
        __syncthreads();
        #pragma unroll
        for (int q = 0; q < 8; ++q) {
            int idx = q * 1024 + tid * 4;
            int rr = idx >> 6, cc = idx & 63;
            float4 mv = *(const float4*)&m_tm1[(size_t)(r0 + rr) * 512 + u0 + cc];
            int s = rr >> 5, e = rr & 7, lo = 16 * ((rr & 31) >> 3);
            float mvs[4] = { mv.x, mv.y, mv.z, mv.w };
            #pragma unroll
            for (int i = 0; i < 4; ++i) {
                int col = cc + i;
                int ln = (col & 15) + lo;
                int t4 = col >> 4;
                Mf[(((s * 4 + t4) * 64 + ln) << 3) + e] = f2bf(mvs[i]);
            }
        }
        __syncthreads();
        const int sgbase = rs * 16 + ch * 4;
        #pragma unroll
        for (int s = 0; s < 4; ++s) {
            bf16x8 bf = *(const bf16x8*)&Mf[((s * 4 + w) * 64 + lane) << 3];
            #pragma unroll
            for (int tb = 0; tb < 4; ++tb) {
                bf16x8 af = *(const bf16x8*)&cwrf[(size_t)((((sgbase + s) * 4 + tb) * 64 + lane)) << 3];
                acc[tb] = __builtin_amdgcn_mfma_f32_16x16x32_bf16(af, bf, acc[tb], 0, 0, 0);
            }
        }
    }
    const int lhi = lane >> 4, llo = lane & 15;
    #pragma unroll
    for (int tb = 0; tb < 4; ++tb) {
        #pragma unroll
        for (int reg = 0; reg < 4; ++reg) {
            int b = tb * 16 + lhi * 4 + reg;
            part[(size_t)rs * 32768 + b * 512 + u0 + w * 16 + llo] = acc[tb][reg];
        }
    }
}

// ---------------------------------------------------------------------------
// K4: c_wlu compare + keep mask + m = m_tm1*keep + c_ww @ h via MFMA bf16.
// A-frags (c_ww) pre-packed by k_cos; embedded read-final (us==1, 32 partials).
// grid 1024 = 256 row-blocks(64) x 4 u-splits(128).
// ---------------------------------------------------------------------------
__global__ __launch_bounds__(256) void k_update(
    const float* __restrict__ m_tm1, const unsigned short* __restrict__ cwwf,
    const unsigned short* __restrict__ hbf,
    const float* __restrict__ minf, const int* __restrict__ idxf,
    const float* __restrict__ rpart, float* out)
{
    __shared__ float keepf[64];
    __shared__ float minS[64];
    __shared__ int   idxS[64];
    const int rb = blockIdx.x >> 2, us = blockIdx.x & 3;
    const int row0 = rb * 64, u0 = us * 128;
    const int tid = threadIdx.x;
    const int w = tid >> 6, lane = tid & 63;
    const int lhi = lane >> 4, llo = lane & 15;
    if (tid < 64) { idxS[tid] = idxf[tid]; minS[tid] = minf[tid]; }
    __syncthreads();
    if (tid < 64) {
        int gr = row0 + tid;
        float f = 1.f;
        #pragma unroll
        for (int b = 0; b < 64; ++b) if (idxS[b] == gr) f = 0.f;
        keepf[tid] = f;
    }
    __syncthreads();
    if (us == 0) {
        #pragma unroll
        for (int q = 0; q < 4; ++q) {
            int idx = q * 1024 + tid * 4;
            int r = idx >> 6, b = idx & 63;
            int g = (row0 + r) * 64 + b;
            float4 cu = *(const float4*)&out[OUT_CWU + g];
            float4 res;
            res.x = (cu.x <= minS[b + 0]) ? 1.f : 0.f;
            res.y = (cu.y <= minS[b + 1]) ? 1.f : 0.f;
            res.z = (cu.z <= minS[b + 2]) ? 1.f : 0.f;
            res.w = (cu.w <= minS[b + 3]) ? 1.f : 0.f;
            *(float4*)&out[OUT_CWLU + g] = res;
        }
    } else if (us == 1) {
        if (tid < 128) {
            int gid = rb * 128 + tid;
            float s = 0.f;
            #pragma unroll 8
            for (int rs = 0; rs < 32; ++rs) s += rpart[(size_t)rs * 32768 + gid];
            out[OUT_READ + gid] = s;
        }
    }
    f32x4 acc[8];
    #pragma unroll
    for (int nt = 0; nt < 8; ++nt) {
        #pragma unroll
        for (int reg = 0; reg < 4; ++reg) {
            int rowl = w * 16 + lhi * 4 + reg;
            acc[nt][reg] = m_tm1[(size_t)(row0 + rowl) * 512 + u0 + nt * 16 + llo]
                         * keepf[rowl];
        }
    }
    #pragma unroll
    for (int s = 0; s < 2; ++s) {
        bf16x8 af = *(const bf16x8*)&cwwf[(size_t)rb * 4096 + (((s * 4 + w) * 64 + lane) << 3)];
        #pragma unroll
        for (int nt = 0; nt < 8; ++nt) {
            int N = (u0 >> 4) + nt;
            bf16x8 bf = *(const bf16x8*)&hbf[((s * 32 + N) * 64 + lane) << 3];
            acc[nt] = __builtin_amdgcn_mfma_f32_16x16x32_bf16(af, bf, acc[nt], 0, 0, 0);
        }
    }
    #pragma unroll
    for (int nt = 0; nt < 8; ++nt) {
        #pragma unroll
        for (int reg = 0; reg < 4; ++reg) {
            int rowl = w * 16 + lhi * 4 + reg;
            out[OUT_M + (size_t)(row0 + rowl) * 512 + u0 + nt * 16 + llo] = acc[nt][reg];
        }
    }
}

extern "C" void kernel_launch(void* const* d_in, const int* in_sizes, int n_in,
                              void* d_out, int out_size, void* d_ws, size_t ws_size,
                              hipStream_t stream)
{
    const float* inputs    = (const float*)d_in[0];
    const float* h_tm1     = (const float*)d_in[1];
    const float* c_tm1     = (const float*)d_in[2];
    const float* r_tm1     = (const float*)d_in[3];
    const float* m_tm1     = (const float*)d_in[4];
    const float* c_wu_tm1  = (const float*)d_in[5];
    const float* c_wlu_tm1 = (const float*)d_in[6];
    const float* c_wr_tm1  = (const float*)d_in[7];
    const float* wk        = (const float*)d_in[8];
    const float* rk        = (const float*)d_in[9];
    const float* bias      = (const float*)d_in[10];
    const float* wgate     = (const float*)d_in[11];
    float* out = (float*)d_out;
    float* ws  = (float*)d_ws;
    float* pre = out + OUT_M;   // scratch in OUT_M region; consumed by k_gates
    unsigned short* nkf  = (unsigned short*)(ws + WS_NKF);
    unsigned short* hbf  = (unsigned short*)(ws + WS_HBF);
    unsigned short* cwwf = (unsigned short*)(ws + WS_CWWF);
    unsigned short* cwrf = (unsigned short*)(ws + WS_CWRF);
    float* rpart = ws + WS_RPART;

    k_preact<<<288, 256, 0, stream>>>(inputs, h_tm1, r_tm1, wk, rk, pre);
    k_gates<<<64, 256, 0, stream>>>(pre, bias, c_tm1, out, nkf, hbf);
    k_cos<<<256, 512, 0, stream>>>(m_tm1, nkf, c_wr_tm1, c_wlu_tm1,
                                   c_wu_tm1, wgate, out, ws + WS_PMIN,
                                   (int*)(ws + WS_PIDX), cwwf, cwrf);
    k_read_part<<<256, 256, 0, stream>>>(m_tm1, cwrf, rpart,
                                         ws + WS_PMIN, (const int*)(ws + WS_PIDX),
                                         ws + WS_MINF, (int*)(ws + WS_IDXF));
    k_update<<<1024, 256, 0, stream>>>(m_tm1, cwwf, hbf,
                                       ws + WS_MINF, (const int*)(ws + WS_IDXF),
                                       rpart, out);
}

// Round 18
// 59.472 us; speedup vs baseline: 1.0612x; 1.0612x over previous
//
#include <hip/hip_runtime.h>
#include <math.h>

// Problem dims: UNITS=512, MEM=16384, BATCH=64
// d_out offsets (floats): h, c, read, m, c_wu, c_wlu, c_wr
#define OUT_H    0
#define OUT_C    32768
#define OUT_READ 65536
#define OUT_M    98304
#define OUT_CWU  8486912
#define OUT_CWLU 9535488
#define OUT_CWR  10584064

// preact scratch (4*294912 floats) lives in OUT_M region, consumed by k_gates
// before k_update overwrites m. Everything else in d_ws (ws_size ~268MB).
// ws offsets (floats) — ushort buffers: floats = ushort_count/2 (CHECKED):
//   nkf  32768 ush = 16384 fl: [0,16384)
//   hbf  32768 ush = 16384 fl: [16384,32768)
//   cwwf 256*4096 ush = 524288 fl: [65664,589952)
//   cwrf 256*4096 ush = 524288 fl: [589952,1114240)
//   rpart 2M fl: [1114240,3211520)
#define WS_NKF   0
#define WS_HBF   16384
#define WS_PMIN  32768      // 256*64 partial min values
#define WS_PIDX  49152      // 256*64 partial min indices (int)
#define WS_MINF  65536      // 64 final min
#define WS_IDXF  65600      // 64 final argmin (int)
#define WS_CWWF  65664
#define WS_CWRF  589952
#define WS_RPART 1114240

typedef short bf16x8 __attribute__((ext_vector_type(8)));
typedef float f32x4  __attribute__((ext_vector_type(4)));

__device__ __forceinline__ float hsig(float x) {
    return fminf(fmaxf(0.2f * x + 0.5f, 0.f), 1.f);
}
__device__ __forceinline__ unsigned short f2bf(float x) {
    unsigned u = __float_as_uint(x);
    return (unsigned short)((u + 0x7fffu + ((u >> 16) & 1u)) >> 16);
}

// ---------------------------------------------------------------------------
// K1: preactivations via MFMA bf16. (verified round 15)
// grid 288 = 72 col-tiles(64) x 4 K-quarters(128). Block 256.
// ---------------------------------------------------------------------------
__global__ __launch_bounds__(256) void k_preact(
    const float* __restrict__ inputs, const float* __restrict__ h_tm1,
    const float* __restrict__ r_tm1, const float* __restrict__ wk,
    const float* __restrict__ rk, float* __restrict__ pre)
{
    __shared__ alignas(16) unsigned short Afr[8192];   // 16 KB
    __shared__ alignas(16) unsigned short Bfr[8192];   // 16 KB
    const int cb = blockIdx.x % 72, kh = blockIdx.x / 72;
    const int vcol0 = cb * 64;
    const float* A; const float* W; int wstride, wcol0;
    if (vcol0 < 2048)      { A = inputs; W = wk; wstride = 2048; wcol0 = vcol0; }
    else if (vcol0 < 4096) { A = h_tm1;  W = rk; wstride = 2560; wcol0 = vcol0 - 2048; }
    else                   { A = r_tm1;  W = rk; wstride = 2560; wcol0 = 2048 + (vcol0 - 4096); }
    const int tid = threadIdx.x;
    const int w = tid >> 6, lane = tid & 63;
    const int lhi = lane >> 4, llo = lane & 15;

    {
        const int koct = tid & 15;
        const int s = koct >> 2;
        #pragma unroll
        for (int i = 0; i < 4; ++i) {
            int row = i * 16 + (tid >> 4);
            const float* src = &A[row * 512 + kh * 128 + koct * 8];
            float4 x0 = *(const float4*)src;
            float4 x1 = *(const float4*)&src[4];
            int ln = (row & 15) + 16 * (koct & 3);
            int rt = row >> 4;
            union { unsigned short hx[8]; uint4 v; } pk;
            pk.hx[0] = f2bf(x0.x); pk.hx[1] = f2bf(x0.y);
            pk.hx[2] = f2bf(x0.z); pk.hx[3] = f2bf(x0.w);
            pk.hx[4] = f2bf(x1.x); pk.hx[5] = f2bf(x1.y);
            pk.hx[6] = f2bf(x1.z); pk.hx[7] = f2bf(x1.w);
            *(uint4*)&Afr[((s * 4 + rt) * 64 + ln) << 3] = pk.v;
        }
    }
    #pragma unroll
    for (int q = 0; q < 8; ++q) {
        int idx = q * 256 + tid;
        int krow = idx >> 4;
        int c4 = (idx & 15) * 4;
        float4 wv = *(const float4*)&W[(size_t)(kh * 128 + krow) * wstride + wcol0 + c4];
        int s = krow >> 5, lh = (krow & 31) >> 3, e = krow & 7;
        float ws4[4] = { wv.x, wv.y, wv.z, wv.w };
        #pragma unroll
        for (int j = 0; j < 4; ++j) {
            int col = c4 + j;
            int tc = col >> 4;
            int ln = (col & 15) + 16 * lh;
            Bfr[(((s * 4 + tc) * 64 + ln) << 3) + e] = f2bf(ws4[j]);
        }
    }
    __syncthreads();

    f32x4 acc[4] = {};
    #pragma unroll
    for (int s = 0; s < 4; ++s) {
        bf16x8 af = *(const bf16x8*)&Afr[((s * 4 + w) * 64 + lane) << 3];
        #pragma unroll
        for (int tc = 0; tc < 4; ++tc) {
            bf16x8 bf = *(const bf16x8*)&Bfr[((s * 4 + tc) * 64 + lane) << 3];
            acc[tc] = __builtin_amdgcn_mfma_f32_16x16x32_bf16(af, bf, acc[tc], 0, 0, 0);
        }
    }

    float* dst = pre + (size_t)kh * 294912;
    #pragma unroll
    for (int tc = 0; tc < 4; ++tc) {
        #pragma unroll
        for (int reg = 0; reg < 4; ++reg) {
            int row = w * 16 + lhi * 4 + reg;
            dst[row * 4608 + vcol0 + tc * 16 + llo] = acc[tc][reg];
        }
    }
}

// ---------------------------------------------------------------------------
// K1c: gate fusion (sums 4 K-quarters) -> h, c; fused L2-norm + bf16 packing.
// grid 64 (one block per batch column b), 256 threads, 2 u per thread.
// ---------------------------------------------------------------------------
__global__ __launch_bounds__(256) void k_gates(
    const float* __restrict__ pre, const float* __restrict__ bias,
    const float* __restrict__ c_tm1, float* __restrict__ out,
    unsigned short* __restrict__ nkf, unsigned short* __restrict__ hbf)
{
    int b = blockIdx.x, t = threadIdx.x;
    const float* p0 = pre + b * 4608;
    const float* p1 = pre + 294912 + b * 4608;
    const float* p2 = pre + 2 * 294912 + b * 4608;
    const float* p3 = pre + 3 * 294912 + b * 4608;
    float hh[2], cc[2];
    #pragma unroll
    for (int q = 0; q < 2; ++q) {
        int u = t + q * 256;
        #define S4(o) (p0[o] + p1[o] + p2[o] + p3[o])
        float xi = S4(u)        + bias[u];
        float xf = S4(512 + u)  + bias[512 + u];
        float xc = S4(1024 + u) + bias[1024 + u];
        float xo = S4(1536 + u) + bias[1536 + u];
        float hi = S4(2048 + u);
        float hf = S4(2560 + u);
        float hc = S4(3072 + u);
        float ho = S4(3584 + u);
        float ri = S4(4096 + u);
        #undef S4
        float ig = hsig(xi + hi + ri);
        float fg = hsig(xf + hf);
        cc[q] = fg * c_tm1[b * 512 + u] + ig * tanhf(xc + hc);
        float og = hsig(xo + ho);
        hh[q] = og * tanhf(cc[q]);
        out[OUT_H + b * 512 + u] = hh[q];
        out[OUT_C + b * 512 + u] = cc[q];
    }
    float ss = hh[0] * hh[0] + hh[1] * hh[1];
    __shared__ float red[4];
    for (int m = 1; m < 64; m <<= 1) ss += __shfl_xor(ss, m);
    if ((t & 63) == 0) red[t >> 6] = ss;
    __syncthreads();
    float tot = red[0] + red[1] + red[2] + red[3];
    float rn = rsqrtf(fmaxf(tot, 1e-12f));
    #pragma unroll
    for (int q = 0; q < 2; ++q) {
        int u = t + q * 256;
        int s = u >> 5, n = b >> 4;
        int lane = (b & 15) + 16 * ((u & 31) >> 3);
        int e = u & 7;
        nkf[(((s * 4 + n) * 64 + lane) << 3) + e] = f2bf(hh[q] * rn);
        int s2 = b >> 5, N = u >> 4;
        int l2 = (u & 15) + 16 * ((b & 31) >> 3);
        int e2 = b & 7;
        hbf[(((s2 * 32 + N) * 64 + l2) << 3) + e2] = f2bf(hh[q]);
    }
}

// ---------------------------------------------------------------------------
// K2: cos GEMM via MFMA bf16, 512 threads (8 waves = 2 waves/SIMD).
// 64 rows/block, grid 256. Wave w: row-tile (w&3), K-half (w>>2); halves
// reduced via LDS. Fused: row-norm, softmax, c_wr/c_wu, min partials,
// c_ww + c_wr A-frag production. (verified round 16)
// ---------------------------------------------------------------------------
__global__ __launch_bounds__(512) void k_cos(
    const float* __restrict__ m_tm1, const unsigned short* __restrict__ nkf,
    const float* __restrict__ cwr_tm1, const float* __restrict__ cwlu_tm1,
    const float* __restrict__ cwu_tm1, const float* __restrict__ wgp,
    float* out, float* __restrict__ pmin, int* __restrict__ pidx,
    unsigned short* __restrict__ cwwf, unsigned short* __restrict__ cwrf)
{
    __shared__ alignas(16) unsigned short Af[4096 * 8];   // 64 KB: all 16 k-steps
    __shared__ alignas(16) float redacc[4][4][64][4];     // 16 KB: K-half reduce
    __shared__ float rn[64];
    __shared__ float pmv[4][64];
    __shared__ int   pmi[4][64];
    const int row0 = blockIdx.x * 64;
    const int tid = threadIdx.x;
    const int w = tid >> 6, lane = tid & 63;
    f32x4 acc[4] = {};
    float ssp[8] = {};

    // --- stage all 64 rows x 512 k as bf16 A-frags; wave w stages row i*8+w ---
    #pragma unroll
    for (int i = 0; i < 8; ++i) {
        int r = i * 8 + w;
        int koct = lane;                           // 0..63 k-octets
        const float* src = &m_tm1[(size_t)(row0 + r) * 512 + koct * 8];
        float4 x0 = *(const float4*)src;
        float4 x1 = *(const float4*)&src[4];
        ssp[i] += x0.x*x0.x + x0.y*x0.y + x0.z*x0.z + x0.w*x0.w
                + x1.x*x1.x + x1.y*x1.y + x1.z*x1.z + x1.w*x1.w;
        int s_l = koct >> 2, rt = r >> 4;
        int ln = ((r & 15) + ((koct & 3) << 4)) ^ (s_l & 7);
        union { unsigned short hx[8]; uint4 v; } pk;
        pk.hx[0] = f2bf(x0.x); pk.hx[1] = f2bf(x0.y);
        pk.hx[2] = f2bf(x0.z); pk.hx[3] = f2bf(x0.w);
        pk.hx[4] = f2bf(x1.x); pk.hx[5] = f2bf(x1.y);
        pk.hx[6] = f2bf(x1.z); pk.hx[7] = f2bf(x1.w);
        *(uint4*)&Af[((s_l * 4 + rt) * 64 + ln) << 3] = pk.v;
    }
    // row sumsq: full-wave reduce, lane 0 writes rn[i*8+w]
    #pragma unroll
    for (int i = 0; i < 8; ++i) {
        float v = ssp[i];
        v += __shfl_xor(v, 1); v += __shfl_xor(v, 2);
        v += __shfl_xor(v, 4); v += __shfl_xor(v, 8);
        v += __shfl_xor(v, 16); v += __shfl_xor(v, 32);
        if (lane == 0) rn[i * 8 + w] = v;
    }
    __syncthreads();

    // --- MFMA: wave w = row-tile (w&3), K-half (w>>2): 8 k-steps ---
    {
        const int wt = w & 3, kh2 = w >> 2;
        for (int s_l = 0; s_l < 8; ++s_l) {
            int s = kh2 * 8 + s_l;
            int lnx = lane ^ (s & 7);
            bf16x8 af = *(const bf16x8*)&Af[((s * 4 + wt) * 64 + lnx) << 3];
            #pragma unroll
            for (int n = 0; n < 4; ++n) {
                bf16x8 bf = *(const bf16x8*)&nkf[((s * 4 + n) * 64 + lane) << 3];
                acc[n] = __builtin_amdgcn_mfma_f32_16x16x32_bf16(af, bf, acc[n], 0, 0, 0);
            }
        }
    }
    // --- reduce K-halves: waves 4-7 store, waves 0-3 add ---
    if (w >= 4) {
        #pragma unroll
        for (int n = 0; n < 4; ++n)
            *(f32x4*)&redacc[w - 4][n][lane][0] = acc[n];
    }
    __syncthreads();
    if (w < 4) {
        #pragma unroll
        for (int n = 0; n < 4; ++n) {
            f32x4 o = *(const f32x4*)&redacc[w][n][lane][0];
            acc[n][0] += o[0]; acc[n][1] += o[1]; acc[n][2] += o[2]; acc[n][3] += o[3];
        }
    }

    const float wg = 1.f / (1.f + expf(-wgp[0]));
    const int lhi = lane >> 4, llo = lane & 15;
    if (w < 4) {
        float rsq[4];
        #pragma unroll
        for (int reg = 0; reg < 4; ++reg) {
            int rl = w * 16 + lhi * 4 + reg;
            rsq[reg] = rsqrtf(fmaxf(rn[rl], 1e-12f));
        }
        float bmv[4] = { INFINITY, INFINITY, INFINITY, INFINITY };
        int   bmi[4] = { 0x7fffffff, 0x7fffffff, 0x7fffffff, 0x7fffffff };
        #pragma unroll
        for (int reg = 0; reg < 4; ++reg) {
            int rl = w * 16 + lhi * 4 + reg;   // r_local in [0,64)
            int r = row0 + rl;
            float c0 = acc[0][reg] * rsq[reg];
            float c1 = acc[1][reg] * rsq[reg];
            float c2 = acc[2][reg] * rsq[reg];
            float c3 = acc[3][reg] * rsq[reg];
            float mx = fmaxf(fmaxf(c0, c1), fmaxf(c2, c3));
            mx = fmaxf(mx, __shfl_xor(mx, 1));
            mx = fmaxf(mx, __shfl_xor(mx, 2));
            mx = fmaxf(mx, __shfl_xor(mx, 4));
            mx = fmaxf(mx, __shfl_xor(mx, 8));
            float e0 = expf(c0 - mx), e1 = expf(c1 - mx);
            float e2 = expf(c2 - mx), e3 = expf(c3 - mx);
            float sm = e0 + e1 + e2 + e3;
            sm += __shfl_xor(sm, 1);
            sm += __shfl_xor(sm, 2);
            sm += __shfl_xor(sm, 4);
            sm += __shfl_xor(sm, 8);
            float inv = 1.f / sm;
            float pv[4] = { e0 * inv, e1 * inv, e2 * inv, e3 * inv };
            #pragma unroll
            for (int n = 0; n < 4; ++n) {
                int g = r * 64 + n * 16 + llo;
                float p = pv[n];
                out[OUT_CWR + g] = p;
                float wr = cwr_tm1[g], wl = cwlu_tm1[g], wu = cwu_tm1[g];
                float cww = wg * wr + (1.f - wg) + wl;
                float cwu = 0.95f * wu + p + cww;
                out[OUT_CWU + g] = cwu;
                // c_ww A-frag for k_update: A[row=rl][k=b=n*16+llo]
                {
                    int rowl16 = lhi * 4 + reg;
                    int s2 = n >> 1;
                    int l2 = rowl16 + 16 * (((n & 1) << 1) + (llo >> 3));
                    Af[(((s2 * 4 + w) * 64 + l2) << 3) + (llo & 7)] = f2bf(cww);
                }
                // c_wr A-frag for k_read_part: A[row=b=n*16+llo][k=rl]
                {
                    int sA = rl >> 5;
                    int lf = llo + 16 * ((rl & 31) >> 3);
                    Af[4096 + (((sA * 4 + n) * 64 + lf) << 3) + (rl & 7)] = f2bf(p);
                }
                if (cwu < bmv[n]) { bmv[n] = cwu; bmi[n] = r; }
            }
        }
        #pragma unroll
        for (int n = 0; n < 4; ++n) {
            #pragma unroll
            for (int mk = 16; mk <= 32; mk <<= 1) {
                float ov = __shfl_xor(bmv[n], mk);
                int   oi = __shfl_xor(bmi[n], mk);
                if (ov < bmv[n] || (ov == bmv[n] && oi < bmi[n])) { bmv[n] = ov; bmi[n] = oi; }
            }
        }
        if (lhi == 0) {
            #pragma unroll
            for (int n = 0; n < 4; ++n) { pmv[w][n * 16 + llo] = bmv[n]; pmi[w][n * 16 + llo] = bmi[n]; }
        }
    }
    __syncthreads();
    // copy both 4096-ushort frag blocks out (512 uint4 each; all 512 threads)
    {
        uint4* dstW = (uint4*)&cwwf[(size_t)blockIdx.x * 4096];
        uint4* dstR = (uint4*)&cwrf[(size_t)blockIdx.x * 4096];
        const uint4* srcp = (const uint4*)Af;
        dstW[tid] = srcp[tid];
        dstR[tid] = srcp[512 + tid];
    }
    if (tid < 64) {
        float bv = pmv[0][tid]; int bi = pmi[0][tid];
        #pragma unroll
        for (int q = 1; q < 4; ++q) {
            float v = pmv[q][tid]; int i2 = pmi[q][tid];
            if (v < bv || (v == bv && i2 < bi)) { bv = v; bi = i2; }
        }
        pmin[blockIdx.x * 64 + tid] = bv;
        pidx[blockIdx.x * 64 + tid] = bi;
    }
}

// ---------------------------------------------------------------------------
// K5: read partials via MFMA bf16 + embedded minfinal. (verified round 14)
// grid 512 = 64 row-splits(256 rows) x 8 u-splits(64).
// ---------------------------------------------------------------------------
__global__ __launch_bounds__(256) void k_read_part(
    const float* __restrict__ m_tm1, const unsigned short* __restrict__ cwrf,
    float* __restrict__ part,
    const float* __restrict__ pmin, const int* __restrict__ pidx,
    float* __restrict__ minf, int* __restrict__ idxf)
{
    __shared__ alignas(16) unsigned short Mf[8192];   // 16 KB: m B-frags
    __shared__ float sv[4]; __shared__ int si[4];
    const int bid = blockIdx.x;
    const int tid = threadIdx.x;
    if (bid < 64) {   // embedded minfinal (block-uniform branch)
        int col = bid;
        float bv = pmin[tid * 64 + col];
        int   bi = pidx[tid * 64 + col];
        for (int mk = 1; mk < 64; mk <<= 1) {
            float ov = __shfl_xor(bv, mk);
            int   oi = __shfl_xor(bi, mk);
            if (ov < bv || (ov == bv && oi < bi)) { bv = ov; bi = oi; }
        }
        if ((tid & 63) == 0) { sv[tid >> 6] = bv; si[tid >> 6] = bi; }
        __syncthreads();
        if (tid == 0) {
            #pragma unroll
            for (int q = 1; q < 4; ++q) {
                if (sv[q] < bv || (sv[q] == bv && si[q] < bi)) { bv = sv[q]; bi = si[q]; }
            }
            minf[col] = bv; idxf[col] = bi;
        }
    }
    const int rs = bid >> 3, us = bid & 7;
    const int row0 = rs * 256, u0 = us * 64;
    const int w = tid >> 6, lane = tid & 63;
    f32x4 acc[4] = {};
    for (int ch = 0; ch < 2; ++ch) {
        const int r0 = row0 + ch * 128;
        __syncthreads();
        #pragma unroll
        for (int q = 0; q < 8; ++q) {
            int idx = q * 1024 + tid * 4;
            int rr = idx >> 6, cc = idx & 63;
            float4 mv = *(const float4*)&m_tm1[(size_t)(r0 + rr) * 512 + u0 + cc];
            int s = rr >> 5, e = rr & 7, lo = 16 * ((rr & 31) >> 3);
            float mvs[4] = { mv.x, mv.y, mv.z, mv.w };
            #pragma unroll
            for (int i = 0; i < 4; ++i) {
                int col = cc + i;
                int ln = (col & 15) + lo;
                int t4 = col >> 4;
                Mf[(((s * 4 + t4) * 64 + ln) << 3) + e] = f2bf(mvs[i]);
            }
        }
        __syncthreads();
        const int sgbase = rs * 8 + ch * 4;
        #pragma unroll
        for (int s = 0; s < 4; ++s) {
            bf16x8 bf = *(const bf16x8*)&Mf[((s * 4 + w) * 64 + lane) << 3];
            #pragma unroll
            for (int tb = 0; tb < 4; ++tb) {
                bf16x8 af = *(const bf16x8*)&cwrf[(size_t)((((sgbase + s) * 4 + tb) * 64 + lane)) << 3];
                acc[tb] = __builtin_amdgcn_mfma_f32_16x16x32_bf16(af, bf, acc[tb], 0, 0, 0);
            }
        }
    }
    const int lhi = lane >> 4, llo = lane & 15;
    #pragma unroll
    for (int tb = 0; tb < 4; ++tb) {
        #pragma unroll
        for (int reg = 0; reg < 4; ++reg) {
            int b = tb * 16 + lhi * 4 + reg;
            part[(size_t)rs * 32768 + b * 512 + u0 + w * 16 + llo] = acc[tb][reg];
        }
    }
}

// ---------------------------------------------------------------------------
// K4: c_wlu compare + keep mask + m = m_tm1*keep + c_ww @ h via MFMA bf16.
// A-frags (c_ww) pre-packed by k_cos; embedded read-final (us==1 blocks).
// grid 1024 = 256 row-blocks(64) x 4 u-splits(128).
// ---------------------------------------------------------------------------
__global__ __launch_bounds__(256) void k_update(
    const float* __restrict__ m_tm1, const unsigned short* __restrict__ cwwf,
    const unsigned short* __restrict__ hbf,
    const float* __restrict__ minf, const int* __restrict__ idxf,
    const float* __restrict__ rpart, float* out)
{
    __shared__ float keepf[64];
    __shared__ float minS[64];
    __shared__ int   idxS[64];
    const int rb = blockIdx.x >> 2, us = blockIdx.x & 3;
    const int row0 = rb * 64, u0 = us * 128;
    const int tid = threadIdx.x;
    const int w = tid >> 6, lane = tid & 63;
    const int lhi = lane >> 4, llo = lane & 15;
    if (tid < 64) { idxS[tid] = idxf[tid]; minS[tid] = minf[tid]; }
    __syncthreads();
    if (tid < 64) {
        int gr = row0 + tid;
        float f = 1.f;
        #pragma unroll
        for (int b = 0; b < 64; ++b) if (idxS[b] == gr) f = 0.f;
        keepf[tid] = f;
    }
    __syncthreads();
    if (us == 0) {
        #pragma unroll
        for (int q = 0; q < 4; ++q) {
            int idx = q * 1024 + tid * 4;
            int r = idx >> 6, b = idx & 63;
            int g = (row0 + r) * 64 + b;
            float4 cu = *(const float4*)&out[OUT_CWU + g];
            float4 res;
            res.x = (cu.x <= minS[b + 0]) ? 1.f : 0.f;
            res.y = (cu.y <= minS[b + 1]) ? 1.f : 0.f;
            res.z = (cu.z <= minS[b + 2]) ? 1.f : 0.f;
            res.w = (cu.w <= minS[b + 3]) ? 1.f : 0.f;
            *(float4*)&out[OUT_CWLU + g] = res;
        }
    } else if (us == 1) {
        if (tid < 128) {
            int gid = rb * 128 + tid;
            float s = 0.f;
            #pragma unroll 8
            for (int rs = 0; rs < 64; ++rs) s += rpart[(size_t)rs * 32768 + gid];
            out[OUT_READ + gid] = s;
        }
    }
    f32x4 acc[8];
    #pragma unroll
    for (int nt = 0; nt < 8; ++nt) {
        #pragma unroll
        for (int reg = 0; reg < 4; ++reg) {
            int rowl = w * 16 + lhi * 4 + reg;
            acc[nt][reg] = m_tm1[(size_t)(row0 + rowl) * 512 + u0 + nt * 16 + llo]
                         * keepf[rowl];
        }
    }
    #pragma unroll
    for (int s = 0; s < 2; ++s) {
        bf16x8 af = *(const bf16x8*)&cwwf[(size_t)rb * 4096 + (((s * 4 + w) * 64 + lane) << 3)];
        #pragma unroll
        for (int nt = 0; nt < 8; ++nt) {
            int N = (u0 >> 4) + nt;
            bf16x8 bf = *(const bf16x8*)&hbf[((s * 32 + N) * 64 + lane) << 3];
            acc[nt] = __builtin_amdgcn_mfma_f32_16x16x32_bf16(af, bf, acc[nt], 0, 0, 0);
        }
    }
    #pragma unroll
    for (int nt = 0; nt < 8; ++nt) {
        #pragma unroll
        for (int reg = 0; reg < 4; ++reg) {
            int rowl = w * 16 + lhi * 4 + reg;
            out[OUT_M + (size_t)(row0 + rowl) * 512 + u0 + nt * 16 + llo] = acc[nt][reg];
        }
    }
}

extern "C" void kernel_launch(void* const* d_in, const int* in_sizes, int n_in,
                              void* d_out, int out_size, void* d_ws, size_t ws_size,
                              hipStream_t stream)
{
    const float* inputs    = (const float*)d_in[0];
    const float* h_tm1     = (const float*)d_in[1];
    const float* c_tm1     = (const float*)d_in[2];
    const float* r_tm1     = (const float*)d_in[3];
    const float* m_tm1     = (const float*)d_in[4];
    const float* c_wu_tm1  = (const float*)d_in[5];
    const float* c_wlu_tm1 = (const float*)d_in[6];
    const float* c_wr_tm1  = (const float*)d_in[7];
    const float* wk        = (const float*)d_in[8];
    const float* rk        = (const float*)d_in[9];
    const float* bias      = (const float*)d_in[10];
    const float* wgate     = (const float*)d_in[11];
    float* out = (float*)d_out;
    float* ws  = (float*)d_ws;
    float* pre = out + OUT_M;   // scratch in OUT_M region; consumed by k_gates
    unsigned short* nkf  = (unsigned short*)(ws + WS_NKF);
    unsigned short* hbf  = (unsigned short*)(ws + WS_HBF);
    unsigned short* cwwf = (unsigned short*)(ws + WS_CWWF);
    unsigned short* cwrf = (unsigned short*)(ws + WS_CWRF);
    float* rpart = ws + WS_RPART;

    k_preact<<<288, 256, 0, stream>>>(inputs, h_tm1, r_tm1, wk, rk, pre);
    k_gates<<<64, 256, 0, stream>>>(pre, bias, c_tm1, out, nkf, hbf);
    k_cos<<<256, 512, 0, stream>>>(m_tm1, nkf, c_wr_tm1, c_wlu_tm1,
                                   c_wu_tm1, wgate, out, ws + WS_PMIN,
                                   (int*)(ws + WS_PIDX), cwwf, cwrf);
    k_read_part<<<512, 256, 0, stream>>>(m_tm1, cwrf, rpart,
                                         ws + WS_PMIN, (const int*)(ws + WS_PIDX),
                                         ws + WS_MINF, (int*)(ws + WS_IDXF));
    k_update<<<1024, 256, 0, stream>>>(m_tm1, cwwf, hbf,
                                       ws + WS_MINF, (const int*)(ws + WS_IDXF),
                                       rpart, out);
}